// Round 10
// baseline (256.745 us; speedup 1.0000x reference)
//
#include <hip/hip_runtime.h>
#include <stdint.h>

#define B_SZ   32768
#define F_SZ   512
#define G_SZ   16
#define L_SZ   64
#define N_COLS 1024   // G*L
#define C_SZ   1000
#define M_TILE 64
#define TILES_PER_BLK 2   // persistent: grid 256 = 1 block/CU, 2 row-tiles each
#define A_STRIDE 520     // ushorts per LDS A row (512+8; keeps 16B alignment, breaks pow2 stride)
#define WT32_STRIDE 36   // floats per transposed 32-row col chunk (32 rows + 4 pad).
                         // 36 = 4 mod 32 words: b128 quartet = (9*col+k)%8 = (col+k)%8 ->
                         // structured writes hit each bank exactly 8x (structural min,
                         // conflict-free); random gather cols spread uniformly.
#define SMEM_BYTES (N_COLS * WT32_STRIDE * 4)   // 147456; A-stage (66560) aliases this
// total static LDS: 147456 + 4096 (gp_s) + 4096 (bias_s) + 1024 (g_s) = 156672 <= 163840

typedef __attribute__((ext_vector_type(8))) short short8;
typedef __attribute__((ext_vector_type(4))) float floatx4;

__device__ __forceinline__ unsigned short f2bf(float f) {
    unsigned int x = __float_as_uint(f);
    x += 0x7fffu + ((x >> 16) & 1u);   // RNE to bf16
    return (unsigned short)(x >> 16);
}

// Raw workgroup barrier WITHOUT the vmcnt(0) drain __syncthreads() implies.
// All sync points in mhc_main are LDS-only hazards -> lgkmcnt(0) suffices.
// Out-stores are never read back; global loads are reg-guarded by the compiler.
// Measured r3: this alone was 133 -> 120 us vs __syncthreads.
__device__ __forceinline__ void barrier_lgkm() {
    __builtin_amdgcn_sched_barrier(0);
    asm volatile("s_waitcnt lgkmcnt(0)" ::: "memory");
    __builtin_amdgcn_s_barrier();
    __builtin_amdgcn_sched_barrier(0);
}

// ---- kernel 1: invert label_ids into CSR; emit column permutation, permuted
//      bias, per-slot group id. Scan rebuilt with __shfl_up (4 barriers total
//      vs 23 full __syncthreads drains of the old Hillis-Steele). ----
__global__ __launch_bounds__(1024) void build_csr_kernel(const int* __restrict__ label_ids,
                                                         const float* __restrict__ bias,
                                                         int* __restrict__ off,
                                                         int* __restrict__ list,
                                                         float* __restrict__ bias_p,
                                                         unsigned char* __restrict__ g_perm) {
    __shared__ int cnt[1024];   // per-class counts (classes padded to 1024)
    __shared__ int cur[1024];   // scatter cursors
    __shared__ int wsum[16];    // per-wave scan totals
    const int t    = threadIdx.x;         // 0..1023 == column index g*64+l
    const int lane = t & 63;
    const int wv   = t >> 6;
    cnt[t] = 0;
    __syncthreads();
    const int lbl = label_ids[t];
    atomicAdd(&cnt[lbl], 1);
    __syncthreads();
    // inclusive scan: wave-local shfl scan + cross-wave scan of 16 totals
    const int v = cnt[t];
    int x = v;
    #pragma unroll
    for (int d = 1; d < 64; d <<= 1) {
        int u = __shfl_up(x, d, 64);
        if (lane >= d) x += u;
    }
    if (lane == 63) wsum[wv] = x;
    __syncthreads();
    if (t < 16) {
        int s = wsum[t];
        #pragma unroll
        for (int d = 1; d < 16; d <<= 1) {
            int u = __shfl_up(s, d, 16);
            if (t >= d) s += u;
        }
        wsum[t] = s;
    }
    __syncthreads();
    const int incl = x + (wv > 0 ? wsum[wv - 1] : 0);
    const int ex   = incl - v;            // exclusive prefix for class t
    cur[t] = ex;
    if (t < C_SZ) off[t] = ex;
    if (t == 0)   off[C_SZ] = N_COLS;     // labels all < C_SZ -> total is 1024
    __syncthreads();
    int pos = atomicAdd(&cur[lbl], 1);
    list[pos]   = t;
    bias_p[pos] = bias[t];
    g_perm[pos] = (unsigned char)(t >> 6);
}

// ---- kernel 2: W f32 -> bf16, rows permuted into CSR-list order ----
__global__ __launch_bounds__(256) void convert_w_kernel(const float* __restrict__ W,
                                                        const int* __restrict__ list,
                                                        unsigned short* __restrict__ Wb) {
    int idx = blockIdx.x * 256 + threadIdx.x;        // float4 index, 131072 total
    int row = idx >> 7;                              // output row j
    int c4  = idx & 127;
    int src = list[row];                             // original column
    const float4* W4 = (const float4*)W;
    float4 v = W4[src * 128 + c4];
    ushort4 u = make_ushort4(f2bf(v.x), f2bf(v.y), f2bf(v.z), f2bf(v.w));
    ((ushort4*)Wb)[idx] = u;
}

// ---- kernel 3: persistent fused GEMM (bf16 MFMA) + weighting + run gather ----
// Grid 256 = 1 block/CU, 2 row-tiles per block. Stage/K-loop = r8 (untouched).
// Epilogue: TWO passes of 32 rows using a 144 KB f32 WT[col][32+4] tile (1
// block/CU owns all 160 KB LDS) -> 6 barriers/tile vs 10. Write = 8x
// ds_write_b128/thread (conflict-free), gather iter = 8x ds_read_b128.
// Stores stay coalesced (thread t <-> class t; r5 measured scattered stores
// cost +30 MB write amplification).
__global__ __launch_bounds__(1024, 4) void mhc_main_kernel(
        const float* __restrict__ feat,            // [B][512] f32
        const float* __restrict__ gp,              // [B][16]  f32
        const unsigned short* __restrict__ Wb,     // [1024][512] bf16, permuted rows
        const float* __restrict__ bias_p,          // [1024] f32, permuted
        const int* __restrict__ off,               // [1001]
        const unsigned char* __restrict__ g_perm,  // [1024] group of each permuted col
        float* __restrict__ out)                   // [B][1000] f32
{
    __shared__ __align__(16) char smem[SMEM_BYTES]; // A-stage aliased with WT tile
    __shared__ float gp_s[M_TILE * G_SZ];           // 64 rows x 16 groups
    __shared__ float bias_s[N_COLS];
    __shared__ unsigned char g_s[N_COLS];

    unsigned short* As = (unsigned short*)smem;
    float* WT = (float*)smem;   // WT[col][36]: 32 rows of this pass + 4 pad

    const int t    = threadIdx.x;
    const int wave = t >> 6;          // 0..15
    const int lane = t & 63;
    const int m16  = lane & 15;
    const int quad = lane >> 4;       // 0..3

    // tile-invariant staging
    bias_s[t] = bias_p[t];
    g_s[t]    = g_perm[t];
    int e0 = 0, e1 = 0;
    if (t < C_SZ) { e0 = off[t]; e1 = off[t + 1]; }

    const floatx4* f4g = (const floatx4*)feat;
    floatx4 pf[8];     // tile-1 A prefetch (32 VGPR, reuses dead acc[0..1] slots)
    float pgp = 0.f;

    #pragma unroll
    for (int it = 0; it < TILES_PER_BLK; ++it) {
        const int tile = blockIdx.x * TILES_PER_BLK + it;
        const int r0   = tile * M_TILE;

        // ---- stage A: 64 rows x 512 f32 -> bf16 LDS ----
        if (it == 0) {
            gp_s[t] = gp[(size_t)r0 * G_SZ + t];
            const floatx4* f4 = f4g + (size_t)r0 * (F_SZ / 4);
            #pragma unroll
            for (int i = 0; i < 8; ++i) {
                int idx = t + i * 1024;            // row = idx/128, c4 = idx%128
                int row = idx >> 7;
                int c4  = idx & 127;
                floatx4 v = f4[idx];
                ushort4 u = make_ushort4(f2bf(v[0]), f2bf(v[1]), f2bf(v[2]), f2bf(v[3]));
                *(ushort4*)(As + row * A_STRIDE + c4 * 4) = u;
            }
        } else {
            barrier_lgkm();   // tile-0 pass-1 gather reads of WT (aliases As) done
            gp_s[t] = pgp;
            #pragma unroll
            for (int i = 0; i < 8; ++i) {
                int idx = t + i * 1024;
                int row = idx >> 7;
                int c4  = idx & 127;
                ushort4 u = make_ushort4(f2bf(pf[i][0]), f2bf(pf[i][1]),
                                         f2bf(pf[i][2]), f2bf(pf[i][3]));
                *(ushort4*)(As + row * A_STRIDE + c4 * 4) = u;
            }
        }
        barrier_lgkm();   // A + gp visible

        const floatx4 zero = {0.f, 0.f, 0.f, 0.f};
        floatx4 acc[4][4];
        #pragma unroll
        for (int i = 0; i < 4; ++i)
            #pragma unroll
            for (int j = 0; j < 4; ++j) acc[i][j] = zero;

        const unsigned short* aBase = As + m16 * A_STRIDE + quad * 8;
        const unsigned short* bBase = Wb + (size_t)(wave * 64 + m16) * F_SZ + quad * 8;

        #pragma unroll 4
        for (int kt = 0; kt < 16; ++kt) {             // K step = 32
            short8 a[4];
            #pragma unroll
            for (int rt = 0; rt < 4; ++rt)
                a[rt] = *(const short8*)(aBase + rt * 16 * A_STRIDE + kt * 32);
            #pragma unroll
            for (int ct = 0; ct < 4; ++ct) {
                short8 b = *(const short8*)(bBase + ct * 16 * F_SZ + kt * 32);
                #pragma unroll
                for (int rt = 0; rt < 4; ++rt)
                    acc[rt][ct] = __builtin_amdgcn_mfma_f32_16x16x32_bf16(a[rt], b, acc[rt][ct], 0, 0, 0);
            }
        }

        barrier_lgkm();   // K-loop A-LDS reads done: WT may overwrite A region

        // ---- epilogue: 2 passes of 32 rows ----
        // pass p covers rows p*32..p*32+31 = acc[2p] (h=0) and acc[2p+1] (h=1)
        #pragma unroll
        for (int p = 0; p < 2; ++p) {
            // staggered tile-1 A prefetch: acc[0..1] dead after pass-0 writes
            if (it == 0 && p == 1) {
                size_t base = (size_t)(tile + 1) * M_TILE * (F_SZ / 4);
                #pragma unroll
                for (int i = 0; i < 8; ++i) pf[i] = f4g[base + t + i * 1024];
                pgp = gp[(size_t)(tile + 1) * M_TILE * G_SZ + t];
            }
            // write: 8x ds_write_b128 per thread (2 half-tiles x 4 ct)
            #pragma unroll
            for (int ct = 0; ct < 4; ++ct) {
                int col = wave * 64 + ct * 16 + m16;
                int g   = g_s[col];
                float bi = bias_s[col];
                #pragma unroll
                for (int h = 0; h < 2; ++h) {
                    floatx4 w;
                    #pragma unroll
                    for (int r = 0; r < 4; ++r) {
                        int rl = h * 16 + quad * 4 + r;          // row 0..31 within pass
                        w[r] = gp_s[(p * 32 + rl) * G_SZ + g] * (acc[p * 2 + h][ct][r] + bi);
                    }
                    *(floatx4*)(WT + col * WT32_STRIDE + h * 16 + quad * 4) = w;
                }
            }
            barrier_lgkm();   // WT visible to gatherers
            if (t < C_SZ) {
                floatx4 s[8];
                #pragma unroll
                for (int k = 0; k < 8; ++k) s[k] = zero;
                const float* cb = WT + e0 * WT32_STRIDE;
                for (int j = e0; j < e1; ++j) {
                    #pragma unroll
                    for (int k = 0; k < 8; ++k)
                        s[k] += *(const floatx4*)(cb + k * 4);
                    cb += WT32_STRIDE;
                }
                size_t rb = (size_t)(r0 + p * 32) * C_SZ + t;    // coalesced column t
                #pragma unroll
                for (int k = 0; k < 8; ++k)
                    #pragma unroll
                    for (int r = 0; r < 4; ++r)
                        out[rb + (size_t)(k * 4 + r) * C_SZ] = s[k][r];
            }
            if (p == 0) barrier_lgkm();   // pass-0 gather reads done before pass-1 writes
        }
    }
}

extern "C" void kernel_launch(void* const* d_in, const int* in_sizes, int n_in,
                              void* d_out, int out_size, void* d_ws, size_t ws_size,
                              hipStream_t stream) {
    const float* feat  = (const float*)d_in[0];
    const float* gp    = (const float*)d_in[1];
    const float* W     = (const float*)d_in[2];
    const float* bias  = (const float*)d_in[3];
    const int* labels  = (const int*)d_in[4];
    float* out = (float*)d_out;

    unsigned short* Wb = (unsigned short*)d_ws;                    // 1 MiB bf16 W (permuted)
    char* base = (char*)d_ws + (1 << 20);
    int* off             = (int*)base;                             // 1001 ints (pad 4 KB)
    int* list            = (int*)(base + 4096);                    // 1024 ints
    float* bias_p        = (float*)(base + 8192);                  // 1024 f32
    unsigned char* g_prm = (unsigned char*)(base + 12288);         // 1024 bytes

    build_csr_kernel<<<1, 1024, 0, stream>>>(labels, bias, off, list, bias_p, g_prm);
    convert_w_kernel<<<(N_COLS * F_SZ / 4) / 256, 256, 0, stream>>>(W, list, Wb);
    mhc_main_kernel<<<B_SZ / (M_TILE * TILES_PER_BLK), 1024, 0, stream>>>(feat, gp, Wb, bias_p, off, g_prm, out);
}

// Round 11
// 253.979 us; speedup vs baseline: 1.0109x; 1.0109x over previous
//
#include <hip/hip_runtime.h>
#include <stdint.h>

#define B_SZ   32768
#define F_SZ   512
#define G_SZ   16
#define L_SZ   64
#define N_COLS 1024   // G*L
#define C_SZ   1000
#define M_TILE 64
#define A_STRIDE 520    // ushorts per LDS A row (512+8; keeps 16B alignment, breaks pow2 stride)
#define WT_STRIDE 20    // floats per transposed weighted col (16 rows + 4 pad).
                        // 20 = odd-multiple-of-4 word stride: b128 quartet = (5*col+quad)%8,
                        // 5 odd -> structured writes hit all 8 quartets evenly (structural-min
                        // 8 rounds/instr) and random gather cols spread uniformly.
#define SMEM_BYTES 81920  // max(A 64*520*2 = 66560, WT 1024*20*4 = 81920)

typedef __attribute__((ext_vector_type(8))) short short8;
typedef __attribute__((ext_vector_type(4))) float floatx4;

__device__ __forceinline__ unsigned short f2bf(float f) {
    unsigned int x = __float_as_uint(f);
    x += 0x7fffu + ((x >> 16) & 1u);   // RNE to bf16
    return (unsigned short)(x >> 16);
}

// Raw workgroup barrier WITHOUT the vmcnt(0) drain __syncthreads() implies.
// All sync points in mhc_main are LDS-only hazards -> lgkmcnt(0) suffices.
// Out-stores are never read back; global loads are reg-guarded by the compiler.
// Measured r3: this alone was 133 -> 120 us vs __syncthreads.
__device__ __forceinline__ void barrier_lgkm() {
    __builtin_amdgcn_sched_barrier(0);
    asm volatile("s_waitcnt lgkmcnt(0)" ::: "memory");
    __builtin_amdgcn_s_barrier();
    __builtin_amdgcn_sched_barrier(0);
}

// ---- kernel 1: invert label_ids into CSR; emit column permutation, permuted
//      bias, per-slot group id. Scan uses __shfl_up (4 barriers total vs 23
//      full __syncthreads drains of the original Hillis-Steele) — validated r10. ----
__global__ __launch_bounds__(1024) void build_csr_kernel(const int* __restrict__ label_ids,
                                                         const float* __restrict__ bias,
                                                         int* __restrict__ off,
                                                         int* __restrict__ list,
                                                         float* __restrict__ bias_p,
                                                         unsigned char* __restrict__ g_perm) {
    __shared__ int cnt[1024];   // per-class counts (classes padded to 1024)
    __shared__ int cur[1024];   // scatter cursors
    __shared__ int wsum[16];    // per-wave scan totals
    const int t    = threadIdx.x;         // 0..1023 == column index g*64+l
    const int lane = t & 63;
    const int wv   = t >> 6;
    cnt[t] = 0;
    __syncthreads();
    const int lbl = label_ids[t];
    atomicAdd(&cnt[lbl], 1);
    __syncthreads();
    // inclusive scan: wave-local shfl scan + cross-wave scan of 16 totals
    const int v = cnt[t];
    int x = v;
    #pragma unroll
    for (int d = 1; d < 64; d <<= 1) {
        int u = __shfl_up(x, d, 64);
        if (lane >= d) x += u;
    }
    if (lane == 63) wsum[wv] = x;
    __syncthreads();
    if (t < 16) {
        int s = wsum[t];
        #pragma unroll
        for (int d = 1; d < 16; d <<= 1) {
            int u = __shfl_up(s, d, 16);
            if (t >= d) s += u;
        }
        wsum[t] = s;
    }
    __syncthreads();
    const int incl = x + (wv > 0 ? wsum[wv - 1] : 0);
    const int ex   = incl - v;            // exclusive prefix for class t
    cur[t] = ex;
    if (t < C_SZ) off[t] = ex;
    if (t == 0)   off[C_SZ] = N_COLS;     // labels all < C_SZ -> total is 1024
    __syncthreads();
    int pos = atomicAdd(&cur[lbl], 1);
    list[pos]   = t;
    bias_p[pos] = bias[t];
    g_perm[pos] = (unsigned char)(t >> 6);
}

// ---- kernel 2: W f32 -> bf16, rows permuted into CSR-list order ----
__global__ __launch_bounds__(256) void convert_w_kernel(const float* __restrict__ W,
                                                        const int* __restrict__ list,
                                                        unsigned short* __restrict__ Wb) {
    int idx = blockIdx.x * 256 + threadIdx.x;        // float4 index, 131072 total
    int row = idx >> 7;                              // output row j
    int c4  = idx & 127;
    int src = list[row];                             // original column
    const float4* W4 = (const float4*)W;
    float4 v = W4[src * 128 + c4];
    ushort4 u = make_ushort4(f2bf(v.x), f2bf(v.y), f2bf(v.z), f2bf(v.w));
    ((ushort4*)Wb)[idx] = u;
}

// ---- kernel 3: fused GEMM (bf16 MFMA) + weighting + contiguous-run gather ----
// Block: 1024 threads = 16 waves. Tile: 64 rows x ALL 1024 (permuted) cols. K=512.
// This is the session-best r7 kernel (measured 117.4 us / 254.5 total), verbatim.
// Session findings baked in:
//  - barrier_lgkm (no vmcnt drain at barriers): -13 us vs __syncthreads (r3)
//  - transposed WT[col][16 rows] stride-20 epilogue: b128 LDS ops, -2.5 us (r7)
//  - coalesced out-stores (thread t <-> class t): scattered stores cost +30 MB
//    L2 partial-line write amplification (r5)
//  - structural wall: acc[4][4]=64 AGPR + 64 VGPR = the 128-reg cap at 4
//    waves/SIMD -> 1 block/CU is forced for this 64-row/16-wave shape; the
//    gather needs all 1024 cols resident so N cannot be tiled; M_TILE=32
//    doubles the per-row B-stream (r1 regression). Occupancy x2, tile
//    prefetch (r8), ping-pong epilogue (r9), barrier halving (r10) all null.
__global__ __launch_bounds__(1024, 4) void mhc_main_kernel(
        const float* __restrict__ feat,            // [B][512] f32
        const float* __restrict__ gp,              // [B][16]  f32
        const unsigned short* __restrict__ Wb,     // [1024][512] bf16, permuted rows
        const float* __restrict__ bias_p,          // [1024] f32, permuted
        const int* __restrict__ off,               // [1001]
        const unsigned char* __restrict__ g_perm,  // [1024] group of each permuted col
        float* __restrict__ out)                   // [B][1000] f32
{
    __shared__ __align__(16) char smem[SMEM_BYTES]; // A-stage aliased with WT tile
    __shared__ float gp_s[M_TILE * G_SZ];           // 64 rows x 16 groups
    __shared__ float bias_s[N_COLS];
    __shared__ unsigned char g_s[N_COLS];

    unsigned short* As = (unsigned short*)smem;
    float* WT = (float*)smem;

    const int t    = threadIdx.x;
    const int wave = t >> 6;          // 0..15
    const int lane = t & 63;
    const int m16  = lane & 15;
    const int quad = lane >> 4;       // 0..3
    const int r0   = blockIdx.x * M_TILE;

    // stage group_probs tile + permuted bias + per-col group
    gp_s[t]   = gp[r0 * G_SZ + t];
    bias_s[t] = bias_p[t];
    g_s[t]    = g_perm[t];

    // this thread's contiguous gather run (pass-invariant, lives in registers)
    int e0 = 0, e1 = 0;
    if (t < C_SZ) { e0 = off[t]; e1 = off[t + 1]; }

    // stage A: 64 rows x 512 f32 -> bf16 LDS, coalesced float4 reads
    {
        const float4* f4 = (const float4*)(feat + (size_t)r0 * F_SZ);
        #pragma unroll
        for (int i = 0; i < 8; ++i) {
            int idx = t + i * 1024;            // row = idx/128, c4 = idx%128
            int row = idx >> 7;
            int c4  = idx & 127;
            float4 v = f4[idx];
            ushort4 u = make_ushort4(f2bf(v.x), f2bf(v.y), f2bf(v.z), f2bf(v.w));
            *(ushort4*)(As + row * A_STRIDE + c4 * 4) = u;
        }
    }
    barrier_lgkm();   // A + gp/bias/g_s visible

    const floatx4 zero = {0.f, 0.f, 0.f, 0.f};
    floatx4 acc[4][4];
    #pragma unroll
    for (int i = 0; i < 4; ++i)
        #pragma unroll
        for (int j = 0; j < 4; ++j) acc[i][j] = zero;

    const unsigned short* aBase = As + m16 * A_STRIDE + quad * 8;
    const unsigned short* bBase = Wb + (size_t)(wave * 64 + m16) * F_SZ + quad * 8;

    #pragma unroll 4
    for (int kt = 0; kt < 16; ++kt) {             // K step = 32
        short8 a[4];
        #pragma unroll
        for (int rt = 0; rt < 4; ++rt)
            a[rt] = *(const short8*)(aBase + rt * 16 * A_STRIDE + kt * 32);
        #pragma unroll
        for (int ct = 0; ct < 4; ++ct) {
            short8 b = *(const short8*)(bBase + ct * 16 * F_SZ + kt * 32);
            #pragma unroll
            for (int rt = 0; rt < 4; ++rt)
                acc[rt][ct] = __builtin_amdgcn_mfma_f32_16x16x32_bf16(a[rt], b, acc[rt][ct], 0, 0, 0);
        }
    }

    // epilogue: 4 passes of 16 rows. Transposed weighted tile -> b128 gather,
    // coalesced b32 stores (thread t == class t).
    #pragma unroll
    for (int p = 0; p < 4; ++p) {
        barrier_lgkm();   // pass 0: K-loop A-LDS reads done; later: prior gather reads done
        #pragma unroll
        for (int ct = 0; ct < 4; ++ct) {
            int col = wave * 64 + ct * 16 + m16;
            int g   = g_s[col];
            float bi = bias_s[col];
            floatx4 w;
            #pragma unroll
            for (int r = 0; r < 4; ++r) {
                int rl = quad * 4 + r;                       // local row 0..15 (C/D layout)
                w[r] = gp_s[(p * 16 + rl) * G_SZ + g] * (acc[p][ct][r] + bi);
            }
            *(floatx4*)(WT + col * WT_STRIDE + quad * 4) = w;  // ds_write_b128
        }
        barrier_lgkm();   // WT visible to gatherers
        if (t < C_SZ) {
            floatx4 s0 = zero, s1 = zero, s2 = zero, s3 = zero;
            for (int j = e0; j < e1; ++j) {
                const float* cb = WT + j * WT_STRIDE;
                s0 += *(const floatx4*)(cb + 0);
                s1 += *(const floatx4*)(cb + 4);
                s2 += *(const floatx4*)(cb + 8);
                s3 += *(const floatx4*)(cb + 12);
            }
            size_t rb = (size_t)(r0 + p * 16) * C_SZ + t;    // coalesced column t
            #pragma unroll
            for (int r = 0; r < 4; ++r) {
                out[rb + (size_t)(r +  0) * C_SZ] = s0[r];
                out[rb + (size_t)(r +  4) * C_SZ] = s1[r];
                out[rb + (size_t)(r +  8) * C_SZ] = s2[r];
                out[rb + (size_t)(r + 12) * C_SZ] = s3[r];
            }
        }
    }
}

extern "C" void kernel_launch(void* const* d_in, const int* in_sizes, int n_in,
                              void* d_out, int out_size, void* d_ws, size_t ws_size,
                              hipStream_t stream) {
    const float* feat  = (const float*)d_in[0];
    const float* gp    = (const float*)d_in[1];
    const float* W     = (const float*)d_in[2];
    const float* bias  = (const float*)d_in[3];
    const int* labels  = (const int*)d_in[4];
    float* out = (float*)d_out;

    unsigned short* Wb = (unsigned short*)d_ws;                    // 1 MiB bf16 W (permuted)
    char* base = (char*)d_ws + (1 << 20);
    int* off             = (int*)base;                             // 1001 ints (pad 4 KB)
    int* list            = (int*)(base + 4096);                    // 1024 ints
    float* bias_p        = (float*)(base + 8192);                  // 1024 f32
    unsigned char* g_prm = (unsigned char*)(base + 12288);         // 1024 bytes

    build_csr_kernel<<<1, 1024, 0, stream>>>(labels, bias, off, list, bias_p, g_prm);
    convert_w_kernel<<<(N_COLS * F_SZ / 4) / 256, 256, 0, stream>>>(W, list, Wb);
    mhc_main_kernel<<<B_SZ / M_TILE, 1024, 0, stream>>>(feat, gp, Wb, bias_p, off, g_prm, out);
}